// Round 16
// baseline (450.257 us; speedup 1.0000x reference)
//
#include <hip/hip_runtime.h>
#include <math.h>

#define NA_TOT 76725
#define NCLS 80
#define LOC_BASE 12276000
#define ANC_BASE 12889800

typedef short s16x8 __attribute__((ext_vector_type(8)));
typedef short s16x4 __attribute__((ext_vector_type(4)));
typedef float fx4 __attribute__((ext_vector_type(4)));

__device__ __forceinline__ unsigned short f2bf(float f) {
  unsigned u = __float_as_uint(f);
  unsigned r = (u + 0x7FFFu + ((u >> 16) & 1u)) >> 16;
  return (unsigned short)r;
}
__device__ __forceinline__ float bf2f(unsigned short h) {
  return __uint_as_float(((unsigned)h) << 16);
}

__global__ void zk(unsigned short* z) { z[threadIdx.x] = 0; }

// weight convert fp32 [O][Cin][taps] -> bf16 [tap][cb][Opad][32] with the
// A-fragment bank swizzle baked in: 16B chunk cc stored at cc ^ ((o>>1)&3).
__global__ __launch_bounds__(256) void wconv(const float* __restrict__ src, unsigned short* __restrict__ dst,
                                             int O, int Opad, int Cin, int taps, int ncb) {
  int idx = blockIdx.x * 256 + threadIdx.x;
  int tot = taps * ncb * Opad * 32;
  if (idx >= tot) return;
  int c32 = idx & 31;
  int r = idx >> 5;
  int o = r % Opad;
  int q = r / Opad;
  int cb = q % ncb;
  int tp = q / ncb;
  int c = cb * 32 + c32;
  float v = (o < O) ? src[((size_t)o * Cin + c) * taps + tp] : 0.f;
  int cc = ((c32 >> 3) ^ ((o >> 1) & 3)) * 8 + (c32 & 7);
  dst[(size_t)(idx & ~31) + cc] = f2bf(v);
}

// NCHW fp32 -> blocked [b][C/32][HW][32] bf16
__global__ __launch_bounds__(256) void nchw2blk(const float* __restrict__ x, unsigned short* __restrict__ y,
                                                int C, int HW) {
  __shared__ float tile[32][65];
  int pb = blockIdx.x * 64, cb = blockIdx.y, b = blockIdx.z;
  int C32 = C >> 5;
  int t = threadIdx.x;
#pragma unroll
  for (int k = 0; k < 8; ++k) {
    int idx = k * 256 + t;
    int c = idx >> 6, p = idx & 63;
    if (pb + p < HW) tile[c][p] = x[((size_t)b * C + cb * 32 + c) * HW + pb + p];
  }
  __syncthreads();
  int pix = t >> 2, co = (t & 3) * 8;
  if (pb + pix < HW) {
    s16x8 v;
#pragma unroll
    for (int j = 0; j < 8; ++j) v[j] = (short)f2bf(tile[co + j][pix]);
    *(s16x8*)(y + (((size_t)b * C32 + cb) * HW + pb + pix) * 32 + co) = v;
  }
}

// nearest 2x upsample + add, blocked layout
__global__ __launch_bounds__(256) void up2add(unsigned short* __restrict__ dst, const unsigned short* __restrict__ src,
                                              int C32, int H, int W) {
  int idx = blockIdx.x * 256 + threadIdx.x;
  int HW = H * W;
  int tot = 2 * C32 * HW * 4;
  if (idx >= tot) return;
  int cv = idx & 3;
  int t = idx >> 2;
  int p = t % HW; t /= HW;
  int cb = t % C32;
  int b = t / C32;
  int h = p / W, w = p - h * W;
  int Hs = H >> 1, Ws = W >> 1;
  size_t di = (((size_t)b * C32 + cb) * HW + p) * 32 + cv * 8;
  size_t si = (((size_t)b * C32 + cb) * (Hs * Ws) + (h >> 1) * Ws + (w >> 1)) * 32 + cv * 8;
  s16x8 d = *(s16x8*)(dst + di);
  s16x8 s = *(const s16x8*)(src + si);
  s16x8 r;
#pragma unroll
  for (int j = 0; j < 8; ++j)
    r[j] = (short)f2bf(bf2f((unsigned short)d[j]) + bf2f((unsigned short)s[j]));
  *(s16x8*)(dst + di) = r;
}

// ---------------- fused multi-level MFMA conv (m97 structure + B dbuf pipeline) ----------------
// Block 256 thr = 4 waves = 4 row-quads. Block tile: 64 Cout x (16 rows x 16 cols).
// Wave tile: 64 Cout x 64 px -> acc[4][4]. Per phase (one 32ch cb):
//   issue stageB(cb+1 -> buf^1); compute(cb) [A + B[cur]]; barrier;
//   stageA(cb+1); vmcnt(0) [B long-landed, only A drain exposed]; barrier.
// B compacted to 336 slots (21 instrs: 6/5/5/5 per wave) so A + 2xB = 79.9KB -> 2 blocks/CU.
struct LvlParams {
  int nlev;
  int nbcum[6];
  int H[5], W[5], CT[5], RT[5], ncb[5], loff[5];
  const unsigned short* x0[5];
  const unsigned short* x1[5];
  const unsigned short* w0[5];
  const unsigned short* w1[5];
  const float* b0[5];
  const float* b1[5];
  unsigned short* y0[5];
  unsigned short* y1[5];
};

template <int TAPS, int MODE>
__global__ __launch_bounds__(256, 2) void conv_mfma(
    LvlParams P, int Opad, int O, int relu, float* __restrict__ fout,
    const unsigned short* __restrict__ zbuf) {
  constexpr int HO = (TAPS == 9) ? 1 : 0;
  constexpr int CW = 16 + 2 * HO;           // 18 or 16
  constexpr int NPIX = CW * CW;             // 324 or 256
  constexpr int NSB0 = (TAPS == 9) ? 6 : 4; // wave0 B staging instrs
  constexpr int NSB1 = (TAPS == 9) ? 5 : 4; // waves1-3 B staging instrs
  constexpr int BSLOT = (NSB0 + 3 * NSB1) * 16;  // 336 or 256
  constexpr int NSA = (TAPS == 9) ? 9 : 1;  // A staging instrs per wave
  constexpr int AROWS = TAPS * 64;          // 576 or 64

  int bx = blockIdx.x;
  int L = 0;
  while (L + 1 < P.nlev && bx >= P.nbcum[L + 1]) ++L;
  int nb = bx - P.nbcum[L];
  int H = P.H[L], W = P.W[L], CT = P.CT[L], RT = P.RT[L];
  int ncbL = P.ncb[L];
  int HW = H * W;
  int ct = nb % CT;
  int tmp = nb / CT;
  int rt = tmp % RT;
  int b = tmp / RT;
  int set = blockIdx.z;
  const unsigned short* x = set ? P.x1[L] : P.x0[L];
  const unsigned short* wgt = set ? P.w1[L] : P.w0[L];
  const float* bias = set ? P.b1[L] : P.b0[L];
  unsigned short* y = set ? P.y1[L] : P.y0[L];

  int tid = threadIdx.x;
  int lane = tid & 63, wv = tid >> 6;
  int wn = wv;              // row-quad
  int l15 = lane & 15, l4 = lane >> 4;

  __shared__ unsigned short lds[(AROWS + 2 * BSLOT) * 32];
  unsigned short* Abuf = lds;                      // [AROWS][32]
  unsigned short* Bbuf = lds + AROWS * 32;         // 2 x [BSLOT][32]

  int r0 = rt * 16 - HO, c0 = ct * 16 - HO;
  int obase = blockIdx.y * 64;

  fx4 acc[4][4];
#pragma unroll
  for (int i = 0; i < 4; ++i)
#pragma unroll
    for (int f = 0; f < 4; ++f) acc[i][f] = fx4{0.f, 0.f, 0.f, 0.f};

  auto stageA = [&](int cb) {
#pragma unroll
    for (int s = 0; s < NSA; ++s) {
      int j = wv * NSA + s;                       // 0..35 (or 0..3)
      int t = (TAPS == 9) ? (j >> 2) : 0;
      int q = (TAPS == 9) ? (j & 3) : j;
      const unsigned short* src =
          wgt + (((size_t)t * ncbL + cb) * Opad + obase + q * 16 + (lane >> 2)) * 32 + (lane & 3) * 8;
      unsigned short* dst = Abuf + j * 512;       // 1 KB per instr, linear
      __builtin_amdgcn_global_load_lds((const __attribute__((address_space(1))) unsigned int*)src,
                                       (__attribute__((address_space(3))) unsigned int*)dst, 16, 0, 0);
    }
  };

  auto stageB = [&](unsigned short* Bb, int cb) {
    int nsw = (wv == 0) ? NSB0 : NSB1;
    int base = (wv == 0) ? 0 : (NSB0 + (wv - 1) * NSB1) * 16;
#pragma unroll
    for (int s = 0; s < NSB0; ++s) {
      if (s < nsw) {
        int ib = base + s * 16;
        int px = ib + (lane >> 2);
        int hr = px / CW, hc = px - hr * CW;
        int h = r0 + hr, wq = c0 + hc;
        bool ok = (px < NPIX) && (h >= 0) && (h < H) && (wq >= 0) && (wq < W);
        int cs = (lane & 3) ^ ((px >> 1) & 3);    // pre-swizzled source chunk
        const unsigned short* src =
            ok ? (x + (((size_t)b * ncbL + cb) * HW + (h * W + wq)) * 32 + cs * 8) : zbuf;
        unsigned short* dst = Bb + ib * 32;
        __builtin_amdgcn_global_load_lds((const __attribute__((address_space(1))) unsigned int*)src,
                                         (__attribute__((address_space(3))) unsigned int*)dst, 16, 0, 0);
      }
    }
  };

  // prologue: stage A(0) + B(0) into buf0, drain fully
  stageA(0);
  stageB(Bbuf, 0);
  asm volatile("s_waitcnt vmcnt(0)" ::: "memory");
  __builtin_amdgcn_s_barrier();

  for (int cb = 0; cb < ncbL; ++cb) {
    unsigned short* Bcur = Bbuf + (size_t)(cb & 1) * BSLOT * 32;
    // prefetch next B into the other buffer; rides under compute
    if (cb + 1 < ncbL) stageB(Bbuf + (size_t)((cb + 1) & 1) * BSLOT * 32, cb + 1);
    __builtin_amdgcn_s_setprio(1);
    if constexpr (TAPS == 9) {
#pragma unroll
      for (int dx = 0; dx < 3; ++dx) {
        s16x8 bw[6];
#pragma unroll
        for (int rr = 0; rr < 6; ++rr) {
          int hpix = (wn * 4 + rr) * CW + (l15 + dx);
          bw[rr] = *(const s16x8*)&Bcur[hpix * 32 + ((l4 ^ ((hpix >> 1) & 3)) * 8)];
        }
#pragma unroll
        for (int dy = 0; dy < 3; ++dy) {
          const int t = dy * 3 + dx;
          s16x8 a[4];
#pragma unroll
          for (int i = 0; i < 4; ++i)
            a[i] = *(const s16x8*)&Abuf[(t * 64 + i * 16 + l15) * 32 + ((l4 ^ ((l15 >> 1) & 3)) * 8)];
#pragma unroll
          for (int f = 0; f < 4; ++f)
#pragma unroll
            for (int i = 0; i < 4; ++i)
              acc[i][f] = __builtin_amdgcn_mfma_f32_16x16x32_bf16(a[i], bw[f + dy], acc[i][f], 0, 0, 0);
        }
      }
    } else {
      s16x8 a[4];
#pragma unroll
      for (int i = 0; i < 4; ++i)
        a[i] = *(const s16x8*)&Abuf[(i * 16 + l15) * 32 + ((l4 ^ ((l15 >> 1) & 3)) * 8)];
#pragma unroll
      for (int f = 0; f < 4; ++f) {
        int hpix = (wn * 4 + f) * CW + l15;
        s16x8 bfr = *(const s16x8*)&Bcur[hpix * 32 + ((l4 ^ ((hpix >> 1) & 3)) * 8)];
#pragma unroll
        for (int i = 0; i < 4; ++i)
          acc[i][f] = __builtin_amdgcn_mfma_f32_16x16x32_bf16(a[i], bfr, acc[i][f], 0, 0, 0);
      }
    }
    __builtin_amdgcn_s_setprio(0);
    if (cb + 1 < ncbL) {
      __builtin_amdgcn_s_barrier();   // all waves done reading A(cb)
      stageA(cb + 1);                 // overwrite A region
      asm volatile("s_waitcnt vmcnt(0)" ::: "memory");  // A exposed; B(cb+1) long-landed
      __builtin_amdgcn_s_barrier();
    }
  }

  int r_base = rt * 16 + wn * 4;
  int c_img = ct * 16 + l15;
  if (MODE == 0) {
    int OC32 = gridDim.y * 2;
#pragma unroll
    for (int i = 0; i < 4; ++i) {
      int o0 = obase + i * 16 + l4 * 4;
      fx4 b4 = *(const fx4*)(bias + o0);
#pragma unroll
      for (int f = 0; f < 4; ++f) {
        int r_img = r_base + f;
        if (r_img < H && c_img < W) {
          int p = r_img * W + c_img;
          size_t base = (((size_t)b * OC32 + (o0 >> 5)) * HW + p) * 32 + (o0 & 31);
          s16x4 pk;
#pragma unroll
          for (int j = 0; j < 4; ++j) {
            float v = acc[i][f][j] + b4[j];
            if (relu) v = fmaxf(v, 0.f);
            pk[j] = (short)f2bf(v);
          }
          *(s16x4*)(y + base) = pk;
        }
      }
    }
  } else if (MODE == 1) {
#pragma unroll
    for (int i = 0; i < 4; ++i) {
      int o0 = obase + i * 16 + l4 * 4;
#pragma unroll
      for (int f = 0; f < 4; ++f) {
        int r_img = r_base + f;
        if (r_img < H && c_img < W && o0 < O) {
          int p = r_img * W + c_img;
          int a_ = o0 / NCLS, c0i = o0 - a_ * NCLS;
          size_t n = (size_t)b * NA_TOT + P.loff[L] + (size_t)p * 9 + a_;
          fx4 v;
#pragma unroll
          for (int j = 0; j < 4; ++j)
            v[j] = 1.f / (1.f + __expf(-(acc[i][f][j] + bias[o0 + j])));
          *(fx4*)(fout + n * NCLS + c0i) = v;
        }
      }
    }
  } else {
#pragma unroll
    for (int i = 0; i < 4; ++i) {
      int o0 = obase + i * 16 + l4 * 4;
#pragma unroll
      for (int f = 0; f < 4; ++f) {
        int r_img = r_base + f;
        if (r_img < H && c_img < W && o0 < O) {
          int p = r_img * W + c_img;
          int a_ = o0 >> 2;
          size_t n = (size_t)b * NA_TOT + P.loff[L] + (size_t)p * 9 + a_;
          fx4 v;
#pragma unroll
          for (int j = 0; j < 4; ++j) v[j] = acc[i][f][j] + bias[o0 + j];
          *(fx4*)(fout + n * 4) = v;
        }
      }
    }
  }
}

__global__ __launch_bounds__(256) void anchors_kernel(float* __restrict__ out) {
  int n = blockIdx.x * blockDim.x + threadIdx.x;
  if (n >= NA_TOT) return;
  int rem, fw;
  float stride;
  if (n < 57600)      { rem = n;         fw = 80; stride = 8.f; }
  else if (n < 72000) { rem = n - 57600; fw = 40; stride = 16.f; }
  else if (n < 75600) { rem = n - 72000; fw = 20; stride = 32.f; }
  else if (n < 76500) { rem = n - 75600; fw = 10; stride = 64.f; }
  else                { rem = n - 76500; fw = 5;  stride = 128.f; }
  int k = rem % 9;
  int cell = rem / 9;
  int xg = cell % fw;
  int yg = cell / fw;
  const float scales[3] = {1.f, 1.2599210498948732f, 1.5874010519681994f};
  const float isr[3] = {1.4142135623730951f, 1.f, 0.70710678118654755f};
  const float sr[3]  = {0.70710678118654755f, 1.f, 1.4142135623730951f};
  int si = k % 3, ri = k / 3;
  float base = 4.f * stride;
  float wv = base * scales[si] * isr[ri];
  float hv = base * scales[si] * sr[ri];
  float cx = ((float)xg + 0.5f) * stride;
  float cy = ((float)yg + 0.5f) * stride;
  out[(size_t)n * 4 + 0] = cx - 0.5f * wv;
  out[(size_t)n * 4 + 1] = cy - 0.5f * hv;
  out[(size_t)n * 4 + 2] = cx + 0.5f * wv;
  out[(size_t)n * 4 + 3] = cy + 0.5f * hv;
}

// ---------------- ws layout (shorts) ----------------
#define W_FL1 0
#define W_FL2 524288
#define W_FL3 786432
#define W_FTD 917504
#define W_CW0 1507328
#define W_RW0 3866624
#define W_CHW 6225920
#define W_RHW 7995392
#define ZBUF_OFF 8290304
#define RA_OFF 8290368
#define P3_OFF 12655168
#define P4_OFF 15931968
#define P5_OFF 16751168
#define T0C_OFF 16955968
// end 21320768 shorts = 42.6 MB

static const int TL_OFF[5] = {0, 3276800, 4096000, 4300800, 4352000};

extern "C" void kernel_launch(void* const* d_in, const int* in_sizes, int n_in,
                              void* d_out, int out_size, void* d_ws, size_t ws_size,
                              hipStream_t stream) {
  const float* c3 = (const float*)d_in[0];
  const float* c4 = (const float*)d_in[1];
  const float* c5 = (const float*)d_in[2];
  const float* p6 = (const float*)d_in[3];
  const float* p7 = (const float*)d_in[4];
  const float* flw[3] = {(const float*)d_in[5], (const float*)d_in[7], (const float*)d_in[9]};
  const float* flb[3] = {(const float*)d_in[6], (const float*)d_in[8], (const float*)d_in[10]};
  const float* ftd_w = (const float*)d_in[11];
  const float* ftd_b = (const float*)d_in[12];
  const float* cwf[4] = {(const float*)d_in[13], (const float*)d_in[15], (const float*)d_in[17], (const float*)d_in[19]};
  const float* cbf[4] = {(const float*)d_in[14], (const float*)d_in[16], (const float*)d_in[18], (const float*)d_in[20]};
  const float* chw = (const float*)d_in[21];
  const float* chb = (const float*)d_in[22];
  const float* rwf[4] = {(const float*)d_in[23], (const float*)d_in[25], (const float*)d_in[27], (const float*)d_in[29]};
  const float* rbf[4] = {(const float*)d_in[24], (const float*)d_in[26], (const float*)d_in[28], (const float*)d_in[30]};
  const float* rhw = (const float*)d_in[31];
  const float* rhb = (const float*)d_in[32];

  unsigned short* ws = (unsigned short*)d_ws;
  unsigned short* zbuf = ws + ZBUF_OFF;
  float* out = (float*)d_out;

  unsigned short* ob = (unsigned short*)d_out;
  unsigned short* x3 = ob;
  unsigned short* x4 = ob + 6553600;
  unsigned short* x5 = ob + 9830400;
  unsigned short* t0r = ob;
  unsigned short* t1r = ob + 4364800;
  unsigned short* xp6 = ws + RA_OFF;
  unsigned short* xp7 = ws + RA_OFF + 51200;
  unsigned short* p4l = ws + RA_OFF + 64000;
  unsigned short* p5l = ws + RA_OFF + 883200;
  unsigned short* p3l = ws + RA_OFF + 1088000;
  unsigned short* t1c = ws + RA_OFF;
  unsigned short* t0c = ws + T0C_OFF;
  unsigned short* p3 = ws + P3_OFF;
  unsigned short* p4 = ws + P4_OFF;
  unsigned short* p5 = ws + P5_OFF;

  zk<<<1, 64, 0, stream>>>(zbuf);

  auto wc = [&](const float* s, unsigned short* d, int O, int Opad, int Cin, int taps) {
    int ncb = Cin / 32;
    int tot = taps * ncb * Opad * 32;
    wconv<<<(tot + 255) / 256, 256, 0, stream>>>(s, d, O, Opad, Cin, taps, ncb);
  };
  wc(flw[0], ws + W_FL1, 256, 256, 2048, 1);
  wc(flw[1], ws + W_FL2, 256, 256, 1024, 1);
  wc(flw[2], ws + W_FL3, 256, 256, 512, 1);
  wc(ftd_w, ws + W_FTD, 256, 256, 256, 9);
  for (int k = 0; k < 4; ++k) wc(cwf[k], ws + W_CW0 + k * 589824, 256, 256, 256, 9);
  for (int k = 0; k < 4; ++k) wc(rwf[k], ws + W_RW0 + k * 589824, 256, 256, 256, 9);
  wc(chw, ws + W_CHW, 720, 768, 256, 9);
  wc(rhw, ws + W_RHW, 36, 64, 256, 9);

  nchw2blk<<<dim3(100, 16, 2), 256, 0, stream>>>(c3, x3, 512, 6400);
  nchw2blk<<<dim3(25, 32, 2), 256, 0, stream>>>(c4, x4, 1024, 1600);
  nchw2blk<<<dim3(7, 64, 2), 256, 0, stream>>>(c5, x5, 2048, 400);
  nchw2blk<<<dim3(2, 8, 2), 256, 0, stream>>>(p6, xp6, 256, 100);
  nchw2blk<<<dim3(1, 8, 2), 256, 0, stream>>>(p7, xp7, 256, 25);

  auto fill = [](LvlParams& P, int nlev, const int* Hs) {
    P.nlev = nlev;
    int cum = 0;
    for (int L = 0; L < nlev; ++L) {
      P.nbcum[L] = cum;
      P.H[L] = Hs[L]; P.W[L] = Hs[L];
      P.CT[L] = (Hs[L] + 15) / 16;
      P.RT[L] = (Hs[L] + 15) / 16;
      cum += 2 * P.CT[L] * P.RT[L];
    }
    P.nbcum[nlev] = cum;
  };

  // ---- FPN laterals: 3 levels fused, 1x1 ----
  {
    int Hs[3] = {20, 40, 80};
    LvlParams P{};
    fill(P, 3, Hs);
    P.ncb[0] = 64; P.ncb[1] = 32; P.ncb[2] = 16;
    P.x0[0] = x5; P.x0[1] = x4; P.x0[2] = x3;
    P.w0[0] = ws + W_FL1; P.w0[1] = ws + W_FL2; P.w0[2] = ws + W_FL3;
    P.b0[0] = flb[0]; P.b0[1] = flb[1]; P.b0[2] = flb[2];
    P.y0[0] = p5l; P.y0[1] = p4l; P.y0[2] = p3l;
    conv_mfma<1, 0><<<dim3(P.nbcum[3], 4, 1), 256, 0, stream>>>(P, 256, 256, 0, nullptr, zbuf);
  }
  up2add<<<dim3((2 * 8 * 1600 * 4 + 255) / 256), 256, 0, stream>>>(p4l, p5l, 8, 40, 40);
  up2add<<<dim3((2 * 8 * 6400 * 4 + 255) / 256), 256, 0, stream>>>(p3l, p4l, 8, 80, 80);

  // ---- shared top-down 3x3 ----
  {
    int Hs[3] = {80, 40, 20};
    LvlParams P{};
    fill(P, 3, Hs);
    for (int L = 0; L < 3; ++L) {
      P.ncb[L] = 8;
      P.w0[L] = ws + W_FTD;
      P.b0[L] = ftd_b;
    }
    P.x0[0] = p3l; P.x0[1] = p4l; P.x0[2] = p5l;
    P.y0[0] = p3; P.y0[1] = p4; P.y0[2] = p5;
    conv_mfma<9, 0><<<dim3(P.nbcum[3], 4, 1), 256, 0, stream>>>(P, 256, 256, 0, nullptr, zbuf);
  }

  // ---- towers: 5 levels, cls(z=0)+reg(z=1) fused ----
  int Hs5[5] = {80, 40, 20, 10, 5};
  int loffs[5] = {0, 57600, 72000, 75600, 76500};
  const unsigned short* feats[5] = {p3, p4, p5, xp6, xp7};

  auto towerP = [&](int layer, const unsigned short* const* xc, const unsigned short* const* xr,
                    unsigned short* yc_base, unsigned short* yr_base) {
    LvlParams P{};
    fill(P, 5, Hs5);
    for (int L = 0; L < 5; ++L) {
      P.ncb[L] = 8;
      P.x0[L] = xc[L];
      P.x1[L] = xr[L];
      P.w0[L] = ws + W_CW0 + layer * 589824;
      P.w1[L] = ws + W_RW0 + layer * 589824;
      P.b0[L] = cbf[layer];
      P.b1[L] = rbf[layer];
      P.y0[L] = yc_base + TL_OFF[L];
      P.y1[L] = yr_base + TL_OFF[L];
    }
    conv_mfma<9, 0><<<dim3(P.nbcum[5], 4, 2), 256, 0, stream>>>(P, 256, 256, 1, nullptr, zbuf);
  };

  const unsigned short* t0c_l[5], *t1c_l[5], *t0r_l[5], *t1r_l[5];
  for (int L = 0; L < 5; ++L) {
    t0c_l[L] = t0c + TL_OFF[L];
    t1c_l[L] = t1c + TL_OFF[L];
    t0r_l[L] = t0r + TL_OFF[L];
    t1r_l[L] = t1r + TL_OFF[L];
  }
  towerP(0, feats, feats, t0c, t0r);
  towerP(1, t0c_l, t0r_l, t1c, t1r);
  towerP(2, t1c_l, t1r_l, t0c, t0r);
  towerP(3, t0c_l, t0r_l, t1c, t1r);

  // ---- reg header first (reads t1r in d_out, writes LOC) ----
  {
    LvlParams P{};
    fill(P, 5, Hs5);
    for (int L = 0; L < 5; ++L) {
      P.ncb[L] = 8;
      P.x0[L] = t1r_l[L];
      P.w0[L] = ws + W_RHW;
      P.b0[L] = rhb;
      P.loff[L] = loffs[L];
    }
    conv_mfma<9, 2><<<dim3(P.nbcum[5], 1, 1), 256, 0, stream>>>(P, 64, 36, 0, out + LOC_BASE, zbuf);
  }
  // ---- cls header (reads t1c in ws, writes cls region) ----
  {
    LvlParams P{};
    fill(P, 5, Hs5);
    for (int L = 0; L < 5; ++L) {
      P.ncb[L] = 8;
      P.x0[L] = t1c_l[L];
      P.w0[L] = ws + W_CHW;
      P.b0[L] = chb;
      P.loff[L] = loffs[L];
    }
    conv_mfma<9, 1><<<dim3(P.nbcum[5], 12, 1), 256, 0, stream>>>(P, 768, 720, 0, out, zbuf);
  }

  anchors_kernel<<<dim3((NA_TOT + 255) / 256), 256, 0, stream>>>(out + ANC_BASE);
}

// Round 17
// 399.565 us; speedup vs baseline: 1.1269x; 1.1269x over previous
//
#include <hip/hip_runtime.h>
#include <math.h>

#define NA_TOT 76725
#define NCLS 80
#define LOC_BASE 12276000
#define ANC_BASE 12889800

typedef short s16x8 __attribute__((ext_vector_type(8)));
typedef short s16x4 __attribute__((ext_vector_type(4)));
typedef float fx4 __attribute__((ext_vector_type(4)));

__device__ __forceinline__ unsigned short f2bf(float f) {
  unsigned u = __float_as_uint(f);
  unsigned r = (u + 0x7FFFu + ((u >> 16) & 1u)) >> 16;
  return (unsigned short)r;
}
__device__ __forceinline__ float bf2f(unsigned short h) {
  return __uint_as_float(((unsigned)h) << 16);
}

__global__ void zk(unsigned short* z) { z[threadIdx.x] = 0; }

// weight convert fp32 [O][Cin][taps] -> bf16 [tap][cb][Opad][32] with the
// A-fragment bank swizzle baked in: 16B chunk cc stored at cc ^ ((o>>1)&3).
__global__ __launch_bounds__(256) void wconv(const float* __restrict__ src, unsigned short* __restrict__ dst,
                                             int O, int Opad, int Cin, int taps, int ncb) {
  int idx = blockIdx.x * 256 + threadIdx.x;
  int tot = taps * ncb * Opad * 32;
  if (idx >= tot) return;
  int c32 = idx & 31;
  int r = idx >> 5;
  int o = r % Opad;
  int q = r / Opad;
  int cb = q % ncb;
  int tp = q / ncb;
  int c = cb * 32 + c32;
  float v = (o < O) ? src[((size_t)o * Cin + c) * taps + tp] : 0.f;
  int cc = ((c32 >> 3) ^ ((o >> 1) & 3)) * 8 + (c32 & 7);
  dst[(size_t)(idx & ~31) + cc] = f2bf(v);
}

// NCHW fp32 -> blocked [b][C/32][HW][32] bf16
__global__ __launch_bounds__(256) void nchw2blk(const float* __restrict__ x, unsigned short* __restrict__ y,
                                                int C, int HW) {
  __shared__ float tile[32][65];
  int pb = blockIdx.x * 64, cb = blockIdx.y, b = blockIdx.z;
  int C32 = C >> 5;
  int t = threadIdx.x;
#pragma unroll
  for (int k = 0; k < 8; ++k) {
    int idx = k * 256 + t;
    int c = idx >> 6, p = idx & 63;
    if (pb + p < HW) tile[c][p] = x[((size_t)b * C + cb * 32 + c) * HW + pb + p];
  }
  __syncthreads();
  int pix = t >> 2, co = (t & 3) * 8;
  if (pb + pix < HW) {
    s16x8 v;
#pragma unroll
    for (int j = 0; j < 8; ++j) v[j] = (short)f2bf(tile[co + j][pix]);
    *(s16x8*)(y + (((size_t)b * C32 + cb) * HW + pb + pix) * 32 + co) = v;
  }
}

// nearest 2x upsample + add, blocked layout
__global__ __launch_bounds__(256) void up2add(unsigned short* __restrict__ dst, const unsigned short* __restrict__ src,
                                              int C32, int H, int W) {
  int idx = blockIdx.x * 256 + threadIdx.x;
  int HW = H * W;
  int tot = 2 * C32 * HW * 4;
  if (idx >= tot) return;
  int cv = idx & 3;
  int t = idx >> 2;
  int p = t % HW; t /= HW;
  int cb = t % C32;
  int b = t / C32;
  int h = p / W, w = p - h * W;
  int Hs = H >> 1, Ws = W >> 1;
  size_t di = (((size_t)b * C32 + cb) * HW + p) * 32 + cv * 8;
  size_t si = (((size_t)b * C32 + cb) * (Hs * Ws) + (h >> 1) * Ws + (w >> 1)) * 32 + cv * 8;
  s16x8 d = *(s16x8*)(dst + di);
  s16x8 s = *(const s16x8*)(src + si);
  s16x8 r;
#pragma unroll
  for (int j = 0; j < 8; ++j)
    r[j] = (short)f2bf(bf2f((unsigned short)d[j]) + bf2f((unsigned short)s[j]));
  *(s16x8*)(dst + di) = r;
}

// ---------------- fused multi-level MFMA conv (m97 structure, 32-Cout slices) ----------------
// Block 256 thr = 4 waves = 4 row-quads. Block tile: 32 Cout x (16 rows x 16 cols).
// Wave tile: 32 Cout x 64 px -> acc[2][4] (32 VGPR). LDS: A 18KB + B 24.6KB = 43KB
// -> 3 blocks/CU (12 waves). Per phase (one 32ch cb): barrier; stage A+B; vmcnt(0);
// barrier; dx-outer compute with bw[6] dedup.
struct LvlParams {
  int nlev;
  int nbcum[6];
  int H[5], W[5], CT[5], RT[5], ncb[5], loff[5];
  const unsigned short* x0[5];
  const unsigned short* x1[5];
  const unsigned short* w0[5];
  const unsigned short* w1[5];
  const float* b0[5];
  const float* b1[5];
  unsigned short* y0[5];
  unsigned short* y1[5];
};

template <int TAPS, int MODE>
__global__ __launch_bounds__(256, 3) void conv_mfma(
    LvlParams P, int Opad, int O, int relu, float* __restrict__ fout,
    const unsigned short* __restrict__ zbuf) {
  constexpr int HO = (TAPS == 9) ? 1 : 0;
  constexpr int CW = 16 + 2 * HO;          // 18 or 16
  constexpr int NPIX = CW * CW;            // 324 or 256
  constexpr int NSB = (TAPS == 9) ? 6 : 4; // B staging instrs per wave
  constexpr int SLOTS = NSB * 64;          // 384 or 256
  constexpr int NAI = TAPS * 2;            // A staging instrs total (18 or 2)
  constexpr int AROWS = TAPS * 32;         // 288 or 32

  int bx = blockIdx.x;
  int L = 0;
  while (L + 1 < P.nlev && bx >= P.nbcum[L + 1]) ++L;
  int nb = bx - P.nbcum[L];
  int H = P.H[L], W = P.W[L], CT = P.CT[L], RT = P.RT[L];
  int ncbL = P.ncb[L];
  int HW = H * W;
  int ct = nb % CT;
  int tmp = nb / CT;
  int rt = tmp % RT;
  int b = tmp / RT;
  int set = blockIdx.z;
  const unsigned short* x = set ? P.x1[L] : P.x0[L];
  const unsigned short* wgt = set ? P.w1[L] : P.w0[L];
  const float* bias = set ? P.b1[L] : P.b0[L];
  unsigned short* y = set ? P.y1[L] : P.y0[L];

  int tid = threadIdx.x;
  int lane = tid & 63, wv = tid >> 6;
  int wn = wv;              // row-quad
  int l15 = lane & 15, l4 = lane >> 4;

  __shared__ unsigned short lds[(AROWS + SLOTS) * 32];
  unsigned short* Abuf = lds;                 // [AROWS][32]
  unsigned short* Bbuf = lds + AROWS * 32;    // [SLOTS][32]

  int r0 = rt * 16 - HO, c0 = ct * 16 - HO;
  int obase = blockIdx.y * 32;

  fx4 acc[2][4];
#pragma unroll
  for (int i = 0; i < 2; ++i)
#pragma unroll
    for (int f = 0; f < 4; ++f) acc[i][f] = fx4{0.f, 0.f, 0.f, 0.f};

  auto stageA = [&](int cb) {
#pragma unroll
    for (int s = 0; s < 5; ++s) {
      int j = wv + 4 * s;                       // strided: counts 5/5/4/4 (or 1/1/0/0)
      if (j < NAI) {
        int t = j >> 1, q = j & 1;
        const unsigned short* src =
            wgt + (((size_t)t * ncbL + cb) * Opad + obase + q * 16 + (lane >> 2)) * 32 + (lane & 3) * 8;
        unsigned short* dst = Abuf + j * 512;   // 1 KB per instr, linear
        __builtin_amdgcn_global_load_lds((const __attribute__((address_space(1))) unsigned int*)src,
                                         (__attribute__((address_space(3))) unsigned int*)dst, 16, 0, 0);
      }
    }
  };

  auto stageB = [&](int cb) {
#pragma unroll
    for (int s = 0; s < NSB; ++s) {
      int ib = wv * (NSB * 16) + s * 16;
      int px = ib + (lane >> 2);
      int hr = px / CW, hc = px - hr * CW;
      int h = r0 + hr, wq = c0 + hc;
      bool ok = (px < NPIX) && (h >= 0) && (h < H) && (wq >= 0) && (wq < W);
      int cs = (lane & 3) ^ ((px >> 1) & 3);    // pre-swizzled source chunk
      const unsigned short* src =
          ok ? (x + (((size_t)b * ncbL + cb) * HW + (h * W + wq)) * 32 + cs * 8) : zbuf;
      unsigned short* dst = Bbuf + ib * 32;
      __builtin_amdgcn_global_load_lds((const __attribute__((address_space(1))) unsigned int*)src,
                                       (__attribute__((address_space(3))) unsigned int*)dst, 16, 0, 0);
    }
  };

  for (int cb = 0; cb < ncbL; ++cb) {
    if (cb) __builtin_amdgcn_s_barrier();       // readers of previous phase done
    stageA(cb);
    stageB(cb);
    asm volatile("s_waitcnt vmcnt(0)" ::: "memory");
    __builtin_amdgcn_s_barrier();
    __builtin_amdgcn_s_setprio(1);
    if constexpr (TAPS == 9) {
#pragma unroll
      for (int dx = 0; dx < 3; ++dx) {
        s16x8 bw[6];
#pragma unroll
        for (int rr = 0; rr < 6; ++rr) {
          int hpix = (wn * 4 + rr) * CW + (l15 + dx);
          bw[rr] = *(const s16x8*)&Bbuf[hpix * 32 + ((l4 ^ ((hpix >> 1) & 3)) * 8)];
        }
#pragma unroll
        for (int dy = 0; dy < 3; ++dy) {
          const int t = dy * 3 + dx;
          s16x8 a[2];
#pragma unroll
          for (int i = 0; i < 2; ++i)
            a[i] = *(const s16x8*)&Abuf[(t * 32 + i * 16 + l15) * 32 + ((l4 ^ ((l15 >> 1) & 3)) * 8)];
#pragma unroll
          for (int f = 0; f < 4; ++f)
#pragma unroll
            for (int i = 0; i < 2; ++i)
              acc[i][f] = __builtin_amdgcn_mfma_f32_16x16x32_bf16(a[i], bw[f + dy], acc[i][f], 0, 0, 0);
        }
      }
    } else {
      s16x8 a[2];
#pragma unroll
      for (int i = 0; i < 2; ++i)
        a[i] = *(const s16x8*)&Abuf[(i * 16 + l15) * 32 + ((l4 ^ ((l15 >> 1) & 3)) * 8)];
#pragma unroll
      for (int f = 0; f < 4; ++f) {
        int hpix = (wn * 4 + f) * CW + l15;
        s16x8 bfr = *(const s16x8*)&Bbuf[hpix * 32 + ((l4 ^ ((hpix >> 1) & 3)) * 8)];
#pragma unroll
        for (int i = 0; i < 2; ++i)
          acc[i][f] = __builtin_amdgcn_mfma_f32_16x16x32_bf16(a[i], bfr, acc[i][f], 0, 0, 0);
      }
    }
    __builtin_amdgcn_s_setprio(0);
  }

  int r_base = rt * 16 + wn * 4;
  int c_img = ct * 16 + l15;
  if (MODE == 0) {
    int OC32 = gridDim.y;
#pragma unroll
    for (int i = 0; i < 2; ++i) {
      int o0 = obase + i * 16 + l4 * 4;
      fx4 b4 = *(const fx4*)(bias + o0);
#pragma unroll
      for (int f = 0; f < 4; ++f) {
        int r_img = r_base + f;
        if (r_img < H && c_img < W) {
          int p = r_img * W + c_img;
          size_t base = (((size_t)b * OC32 + (o0 >> 5)) * HW + p) * 32 + (o0 & 31);
          s16x4 pk;
#pragma unroll
          for (int j = 0; j < 4; ++j) {
            float v = acc[i][f][j] + b4[j];
            if (relu) v = fmaxf(v, 0.f);
            pk[j] = (short)f2bf(v);
          }
          *(s16x4*)(y + base) = pk;
        }
      }
    }
  } else if (MODE == 1) {
#pragma unroll
    for (int i = 0; i < 2; ++i) {
      int o0 = obase + i * 16 + l4 * 4;
#pragma unroll
      for (int f = 0; f < 4; ++f) {
        int r_img = r_base + f;
        if (r_img < H && c_img < W && o0 < O) {
          int p = r_img * W + c_img;
          int a_ = o0 / NCLS, c0i = o0 - a_ * NCLS;
          size_t n = (size_t)b * NA_TOT + P.loff[L] + (size_t)p * 9 + a_;
          fx4 v;
#pragma unroll
          for (int j = 0; j < 4; ++j)
            v[j] = 1.f / (1.f + __expf(-(acc[i][f][j] + bias[o0 + j])));
          *(fx4*)(fout + n * NCLS + c0i) = v;
        }
      }
    }
  } else {
#pragma unroll
    for (int i = 0; i < 2; ++i) {
      int o0 = obase + i * 16 + l4 * 4;
#pragma unroll
      for (int f = 0; f < 4; ++f) {
        int r_img = r_base + f;
        if (r_img < H && c_img < W && o0 < O) {
          int p = r_img * W + c_img;
          int a_ = o0 >> 2;
          size_t n = (size_t)b * NA_TOT + P.loff[L] + (size_t)p * 9 + a_;
          fx4 v;
#pragma unroll
          for (int j = 0; j < 4; ++j) v[j] = acc[i][f][j] + bias[o0 + j];
          *(fx4*)(fout + n * 4) = v;
        }
      }
    }
  }
}

__global__ __launch_bounds__(256) void anchors_kernel(float* __restrict__ out) {
  int n = blockIdx.x * blockDim.x + threadIdx.x;
  if (n >= NA_TOT) return;
  int rem, fw;
  float stride;
  if (n < 57600)      { rem = n;         fw = 80; stride = 8.f; }
  else if (n < 72000) { rem = n - 57600; fw = 40; stride = 16.f; }
  else if (n < 75600) { rem = n - 72000; fw = 20; stride = 32.f; }
  else if (n < 76500) { rem = n - 75600; fw = 10; stride = 64.f; }
  else                { rem = n - 76500; fw = 5;  stride = 128.f; }
  int k = rem % 9;
  int cell = rem / 9;
  int xg = cell % fw;
  int yg = cell / fw;
  const float scales[3] = {1.f, 1.2599210498948732f, 1.5874010519681994f};
  const float isr[3] = {1.4142135623730951f, 1.f, 0.70710678118654755f};
  const float sr[3]  = {0.70710678118654755f, 1.f, 1.4142135623730951f};
  int si = k % 3, ri = k / 3;
  float base = 4.f * stride;
  float wv = base * scales[si] * isr[ri];
  float hv = base * scales[si] * sr[ri];
  float cx = ((float)xg + 0.5f) * stride;
  float cy = ((float)yg + 0.5f) * stride;
  out[(size_t)n * 4 + 0] = cx - 0.5f * wv;
  out[(size_t)n * 4 + 1] = cy - 0.5f * hv;
  out[(size_t)n * 4 + 2] = cx + 0.5f * wv;
  out[(size_t)n * 4 + 3] = cy + 0.5f * hv;
}

// ---------------- ws layout (shorts) ----------------
#define W_FL1 0
#define W_FL2 524288
#define W_FL3 786432
#define W_FTD 917504
#define W_CW0 1507328
#define W_RW0 3866624
#define W_CHW 6225920
#define W_RHW 7995392
#define ZBUF_OFF 8290304
#define RA_OFF 8290368
#define P3_OFF 12655168
#define P4_OFF 15931968
#define P5_OFF 16751168
#define T0C_OFF 16955968
// end 21320768 shorts = 42.6 MB

static const int TL_OFF[5] = {0, 3276800, 4096000, 4300800, 4352000};

extern "C" void kernel_launch(void* const* d_in, const int* in_sizes, int n_in,
                              void* d_out, int out_size, void* d_ws, size_t ws_size,
                              hipStream_t stream) {
  const float* c3 = (const float*)d_in[0];
  const float* c4 = (const float*)d_in[1];
  const float* c5 = (const float*)d_in[2];
  const float* p6 = (const float*)d_in[3];
  const float* p7 = (const float*)d_in[4];
  const float* flw[3] = {(const float*)d_in[5], (const float*)d_in[7], (const float*)d_in[9]};
  const float* flb[3] = {(const float*)d_in[6], (const float*)d_in[8], (const float*)d_in[10]};
  const float* ftd_w = (const float*)d_in[11];
  const float* ftd_b = (const float*)d_in[12];
  const float* cwf[4] = {(const float*)d_in[13], (const float*)d_in[15], (const float*)d_in[17], (const float*)d_in[19]};
  const float* cbf[4] = {(const float*)d_in[14], (const float*)d_in[16], (const float*)d_in[18], (const float*)d_in[20]};
  const float* chw = (const float*)d_in[21];
  const float* chb = (const float*)d_in[22];
  const float* rwf[4] = {(const float*)d_in[23], (const float*)d_in[25], (const float*)d_in[27], (const float*)d_in[29]};
  const float* rbf[4] = {(const float*)d_in[24], (const float*)d_in[26], (const float*)d_in[28], (const float*)d_in[30]};
  const float* rhw = (const float*)d_in[31];
  const float* rhb = (const float*)d_in[32];

  unsigned short* ws = (unsigned short*)d_ws;
  unsigned short* zbuf = ws + ZBUF_OFF;
  float* out = (float*)d_out;

  unsigned short* ob = (unsigned short*)d_out;
  unsigned short* x3 = ob;
  unsigned short* x4 = ob + 6553600;
  unsigned short* x5 = ob + 9830400;
  unsigned short* t0r = ob;
  unsigned short* t1r = ob + 4364800;
  unsigned short* xp6 = ws + RA_OFF;
  unsigned short* xp7 = ws + RA_OFF + 51200;
  unsigned short* p4l = ws + RA_OFF + 64000;
  unsigned short* p5l = ws + RA_OFF + 883200;
  unsigned short* p3l = ws + RA_OFF + 1088000;
  unsigned short* t1c = ws + RA_OFF;
  unsigned short* t0c = ws + T0C_OFF;
  unsigned short* p3 = ws + P3_OFF;
  unsigned short* p4 = ws + P4_OFF;
  unsigned short* p5 = ws + P5_OFF;

  zk<<<1, 64, 0, stream>>>(zbuf);

  auto wc = [&](const float* s, unsigned short* d, int O, int Opad, int Cin, int taps) {
    int ncb = Cin / 32;
    int tot = taps * ncb * Opad * 32;
    wconv<<<(tot + 255) / 256, 256, 0, stream>>>(s, d, O, Opad, Cin, taps, ncb);
  };
  wc(flw[0], ws + W_FL1, 256, 256, 2048, 1);
  wc(flw[1], ws + W_FL2, 256, 256, 1024, 1);
  wc(flw[2], ws + W_FL3, 256, 256, 512, 1);
  wc(ftd_w, ws + W_FTD, 256, 256, 256, 9);
  for (int k = 0; k < 4; ++k) wc(cwf[k], ws + W_CW0 + k * 589824, 256, 256, 256, 9);
  for (int k = 0; k < 4; ++k) wc(rwf[k], ws + W_RW0 + k * 589824, 256, 256, 256, 9);
  wc(chw, ws + W_CHW, 720, 736, 256, 9);
  wc(rhw, ws + W_RHW, 36, 64, 256, 9);

  nchw2blk<<<dim3(100, 16, 2), 256, 0, stream>>>(c3, x3, 512, 6400);
  nchw2blk<<<dim3(25, 32, 2), 256, 0, stream>>>(c4, x4, 1024, 1600);
  nchw2blk<<<dim3(7, 64, 2), 256, 0, stream>>>(c5, x5, 2048, 400);
  nchw2blk<<<dim3(2, 8, 2), 256, 0, stream>>>(p6, xp6, 256, 100);
  nchw2blk<<<dim3(1, 8, 2), 256, 0, stream>>>(p7, xp7, 256, 25);

  auto fill = [](LvlParams& P, int nlev, const int* Hs) {
    P.nlev = nlev;
    int cum = 0;
    for (int L = 0; L < nlev; ++L) {
      P.nbcum[L] = cum;
      P.H[L] = Hs[L]; P.W[L] = Hs[L];
      P.CT[L] = (Hs[L] + 15) / 16;
      P.RT[L] = (Hs[L] + 15) / 16;
      cum += 2 * P.CT[L] * P.RT[L];
    }
    P.nbcum[nlev] = cum;
  };

  // ---- FPN laterals: 3 levels fused, 1x1 ----
  {
    int Hs[3] = {20, 40, 80};
    LvlParams P{};
    fill(P, 3, Hs);
    P.ncb[0] = 64; P.ncb[1] = 32; P.ncb[2] = 16;
    P.x0[0] = x5; P.x0[1] = x4; P.x0[2] = x3;
    P.w0[0] = ws + W_FL1; P.w0[1] = ws + W_FL2; P.w0[2] = ws + W_FL3;
    P.b0[0] = flb[0]; P.b0[1] = flb[1]; P.b0[2] = flb[2];
    P.y0[0] = p5l; P.y0[1] = p4l; P.y0[2] = p3l;
    conv_mfma<1, 0><<<dim3(P.nbcum[3], 8, 1), 256, 0, stream>>>(P, 256, 256, 0, nullptr, zbuf);
  }
  up2add<<<dim3((2 * 8 * 1600 * 4 + 255) / 256), 256, 0, stream>>>(p4l, p5l, 8, 40, 40);
  up2add<<<dim3((2 * 8 * 6400 * 4 + 255) / 256), 256, 0, stream>>>(p3l, p4l, 8, 80, 80);

  // ---- shared top-down 3x3 ----
  {
    int Hs[3] = {80, 40, 20};
    LvlParams P{};
    fill(P, 3, Hs);
    for (int L = 0; L < 3; ++L) {
      P.ncb[L] = 8;
      P.w0[L] = ws + W_FTD;
      P.b0[L] = ftd_b;
    }
    P.x0[0] = p3l; P.x0[1] = p4l; P.x0[2] = p5l;
    P.y0[0] = p3; P.y0[1] = p4; P.y0[2] = p5;
    conv_mfma<9, 0><<<dim3(P.nbcum[3], 8, 1), 256, 0, stream>>>(P, 256, 256, 0, nullptr, zbuf);
  }

  // ---- towers: 5 levels, cls(z=0)+reg(z=1) fused ----
  int Hs5[5] = {80, 40, 20, 10, 5};
  int loffs[5] = {0, 57600, 72000, 75600, 76500};
  const unsigned short* feats[5] = {p3, p4, p5, xp6, xp7};

  auto towerP = [&](int layer, const unsigned short* const* xc, const unsigned short* const* xr,
                    unsigned short* yc_base, unsigned short* yr_base) {
    LvlParams P{};
    fill(P, 5, Hs5);
    for (int L = 0; L < 5; ++L) {
      P.ncb[L] = 8;
      P.x0[L] = xc[L];
      P.x1[L] = xr[L];
      P.w0[L] = ws + W_CW0 + layer * 589824;
      P.w1[L] = ws + W_RW0 + layer * 589824;
      P.b0[L] = cbf[layer];
      P.b1[L] = rbf[layer];
      P.y0[L] = yc_base + TL_OFF[L];
      P.y1[L] = yr_base + TL_OFF[L];
    }
    conv_mfma<9, 0><<<dim3(P.nbcum[5], 8, 2), 256, 0, stream>>>(P, 256, 256, 1, nullptr, zbuf);
  };

  const unsigned short* t0c_l[5], *t1c_l[5], *t0r_l[5], *t1r_l[5];
  for (int L = 0; L < 5; ++L) {
    t0c_l[L] = t0c + TL_OFF[L];
    t1c_l[L] = t1c + TL_OFF[L];
    t0r_l[L] = t0r + TL_OFF[L];
    t1r_l[L] = t1r + TL_OFF[L];
  }
  towerP(0, feats, feats, t0c, t0r);
  towerP(1, t0c_l, t0r_l, t1c, t1r);
  towerP(2, t1c_l, t1r_l, t0c, t0r);
  towerP(3, t0c_l, t0r_l, t1c, t1r);

  // ---- reg header first (reads t1r in d_out, writes LOC) ----
  {
    LvlParams P{};
    fill(P, 5, Hs5);
    for (int L = 0; L < 5; ++L) {
      P.ncb[L] = 8;
      P.x0[L] = t1r_l[L];
      P.w0[L] = ws + W_RHW;
      P.b0[L] = rhb;
      P.loff[L] = loffs[L];
    }
    conv_mfma<9, 2><<<dim3(P.nbcum[5], 2, 1), 256, 0, stream>>>(P, 64, 36, 0, out + LOC_BASE, zbuf);
  }
  // ---- cls header (reads t1c in ws, writes cls region) ----
  {
    LvlParams P{};
    fill(P, 5, Hs5);
    for (int L = 0; L < 5; ++L) {
      P.ncb[L] = 8;
      P.x0[L] = t1c_l[L];
      P.w0[L] = ws + W_CHW;
      P.b0[L] = chb;
      P.loff[L] = loffs[L];
    }
    conv_mfma<9, 1><<<dim3(P.nbcum[5], 23, 1), 256, 0, stream>>>(P, 736, 720, 0, out, zbuf);
  }

  anchors_kernel<<<dim3((NA_TOT + 255) / 256), 256, 0, stream>>>(out + ANC_BASE);
}